// Round 2
// baseline (545.811 us; speedup 1.0000x reference)
//
#include <hip/hip_runtime.h>

// Shapes (fixed by the reference): B=4, S=2048 -> M=8192; D_IN=K=4096; D_OUT=N=4096; R=16
constexpr int M = 8192;
constexpr int N = 4096;
constexpr int K = 4096;
constexpr float SCALING = 2.0f; // 32/16

typedef __bf16 bf16x8 __attribute__((ext_vector_type(8)));
typedef __bf16 bf16x4 __attribute__((ext_vector_type(4)));
typedef float  f32x4  __attribute__((ext_vector_type(4)));

// ---------------------------------------------------------------------------
// Kernel 1: cast x (fp32) -> bf16, 8 elements / thread (unchanged)
// ---------------------------------------------------------------------------
__global__ __launch_bounds__(256) void qlora_cast_x(const float* __restrict__ x,
                                                    __bf16* __restrict__ xb) {
    const size_t i = ((size_t)blockIdx.x * 256 + threadIdx.x) * 8;
    const float4 v0 = *(const float4*)(x + i);
    const float4 v1 = *(const float4*)(x + i + 4);
    bf16x8 o;
    o[0] = (__bf16)v0.x; o[1] = (__bf16)v0.y; o[2] = (__bf16)v0.z; o[3] = (__bf16)v0.w;
    o[4] = (__bf16)v1.x; o[5] = (__bf16)v1.y; o[6] = (__bf16)v1.z; o[7] = (__bf16)v1.w;
    *(bf16x8*)(xb + i) = o;
}

// ---------------------------------------------------------------------------
// Kernel 2: W_eff[o,i] = w_int[o,i]*scale + 2 * sum_r loraB[o,r]*loraA[r,i]
// (unchanged from round 1: o-tile=16/block, lora_A LDS-staged)
// ---------------------------------------------------------------------------
__global__ __launch_bounds__(256) void qlora_prep_w(const int* __restrict__ wi,
                                                    const float* __restrict__ wscale,
                                                    const float* __restrict__ lA,
                                                    const float* __restrict__ lB,
                                                    __bf16* __restrict__ W) {
    __shared__ __align__(16) float As[16][1028];
    const int t  = threadIdx.x;
    const int ol = t >> 4;
    const int kk = t & 15;
    const int o  = blockIdx.x * 16 + ol;
    const float s = wscale[0];
    float b[16];
#pragma unroll
    for (int r = 0; r < 16; ++r) b[r] = lB[o * 16 + r];

    for (int c = 0; c < 4; ++c) {
        const int c0 = c * 1024;
#pragma unroll
        for (int i = 0; i < 16; ++i) {
            const int idx = t + i * 256;
            const int r   = idx >> 8;
            const int c4  = idx & 255;
            const float4 v = *(const float4*)(lA + r * K + c0 + c4 * 4);
            *(float4*)(&As[r][c4 * 4]) = v;
        }
        __syncthreads();
#pragma unroll
        for (int j = 0; j < 16; ++j) {
            const int k4 = kk + j * 16;
            const int kg = c0 + k4 * 4;
            const int4 w4 = *(const int4*)(wi + (size_t)o * K + kg);
            float a0 = 0.f, a1 = 0.f, a2 = 0.f, a3 = 0.f;
#pragma unroll
            for (int r = 0; r < 16; ++r) {
                const float4 a4 = *(const float4*)(&As[r][k4 * 4]);
                a0 += b[r] * a4.x; a1 += b[r] * a4.y;
                a2 += b[r] * a4.z; a3 += b[r] * a4.w;
            }
            bf16x4 v;
            v[0] = (__bf16)((float)w4.x * s + SCALING * a0);
            v[1] = (__bf16)((float)w4.y * s + SCALING * a1);
            v[2] = (__bf16)((float)w4.z * s + SCALING * a2);
            v[3] = (__bf16)((float)w4.w * s + SCALING * a3);
            *(bf16x4*)(W + (size_t)o * K + kg) = v;
        }
        __syncthreads();
    }
}

// ---------------------------------------------------------------------------
// Kernel 3: C[M,N] = Xbf[M,K] @ Wbf[N,K]^T
// 256x256 tile, 8 waves (2Mx4N).  NEW: BK=32 with FOUR LDS buffers
// (4 x (A 16KB + B 16KB) = 128 KiB), deep pipeline:
//   step s: stage(s+3) issued at phase A; boundary wait = vmcnt(8)
//   -> only stage(s+1)'s 4 loads must have landed; stage(s+2)/(s+3)'s 8
//   loads stay in flight ACROSS the barrier (counted-vmcnt, T4).
//   Issue->wait distance = 3 steps = 6 phases (~1200 cyc) > HBM ~900 cyc.
// Per step: 2 phases x 16 MFMA (fm0-3 | fm4-7, fn0-3; B frags live in regs).
// Buffer race: stage(s+3) targets buf (s+3)&3 == (s-1)&3, whose readers all
// passed the end-of-(s-1) boundary barrier before phase A of s issues.
// Per-wave vmcnt counts its own 4 loads/step; barrier after the wait makes
// all waves' stages visible collectively.
//
// LDS swizzle (BK=32: row = 32 elems = 4 x 16B chunks): chunk c of row r is
// stored at slot c ^ ((r>>1)&3).  Read slot = quad ^ ((lb>>1)&3) -> within
// each 16-lane subgroup, bank-start 16*(lb&1)+4*((lb>>1)&3 ^ quad) takes 8
// distinct values x 2 lanes = 2-way = free.  (Using r&3 instead would alias
// lanes lb/lb+4 -> 4-way conflict.)
// Staging: one async16 = 64 lanes x 16B = 16 rows x 4 slots; lane l -> row
// l>>2, slot l&3, fetching global chunk (l&3) ^ ((l>>3)&3).  Both 16-row
// groups of a wave's 32 rows share the formula (row offsets 0,16 are == 0
// mod 8 after >>1 ... verified: ((16+x)>>1)&3 == ((x)>>1)&3 for x<4 groups).
// ---------------------------------------------------------------------------
__device__ __forceinline__ void async16(const __bf16* g, __bf16* l) {
    __builtin_amdgcn_global_load_lds(
        (const __attribute__((address_space(1))) unsigned int*)(unsigned long long)g,
        (__attribute__((address_space(3))) unsigned int*)(unsigned int)(unsigned long long)l,
        16, 0, 0);
}

__global__ __launch_bounds__(512, 2) void qlora_gemm_bt(const __bf16* __restrict__ A,
                                                        const __bf16* __restrict__ B,
                                                        float* __restrict__ C) {
    __shared__ __align__(16) __bf16 Lds[65536];   // 4 bufs x [A 8192 | B 8192] elems

    const int tid  = threadIdx.x;
    const int w    = tid >> 6;       // wave 0..7
    const int lane = tid & 63;
    const int quad = lane >> 4;      // 0..3
    const int lb   = lane & 15;
    const int wm   = w >> 2;         // 0..1
    const int wn   = w & 3;          // 0..3

    // XCD-aware bijective swizzle (512 blocks = 8 XCDs x 64)
    const int swz = (blockIdx.x & 7) * 64 + (blockIdx.x >> 3);
    const int bx  = swz >> 5;        // 0..15
    const int by  = swz & 31;        // 0..31
    const size_t mBase = (size_t)by * 256;
    const size_t nBase = (size_t)bx * 256;

    // ---- staging: wave w owns rows [w*32, w*32+32) of A and of B ----
    const int r16 = lane >> 2;                       // 0..15
    const int ch  = ((lane & 3) ^ ((lane >> 3) & 3)) * 8;  // swizzled global chunk
    const __bf16* gA = A + (mBase + w * 32 + r16) * K + ch;
    const __bf16* gB = B + (nBase + w * 32 + r16) * K + ch;

    // ---- ds_read offsets (elements) ----
    const int sw  = (quad ^ ((lb >> 1) & 3)) * 8;
    const int roA = (wm * 128 + lb) * 32 + sw;       // + fm*512
    const int roB = (wn * 64 + lb) * 32 + sw;        // + fn*512

    f32x4 acc[8][4] = {};

    auto stage = [&](int buf, int s) {
        __bf16* la  = Lds + buf * 16384 + w * 1024;
        __bf16* lbp = la + 8192;
        const __bf16* pa = gA + (size_t)s * 32;
        const __bf16* pb = gB + (size_t)s * 32;
        async16(pa, la);
        async16(pa + (size_t)16 * K, la + 512);
        async16(pb, lbp);
        async16(pb + (size_t)16 * K, lbp + 512);
    };

    auto MF = [](bf16x8 a, bf16x8 b, f32x4 c) {
        return __builtin_amdgcn_mfma_f32_16x16x32_bf16(a, b, c, 0, 0, 0);
    };

#define VM8 asm volatile("s_waitcnt vmcnt(8)" ::: "memory")
#define VM4 asm volatile("s_waitcnt vmcnt(4)" ::: "memory")
#define VM0 asm volatile("s_waitcnt vmcnt(0)" ::: "memory")
#define NOWAIT ((void)0)

#define GSTEP(BUF, DOSTAGE, SNEXT, WAITSTMT)                                 \
  {                                                                          \
    const __bf16* Ab = Lds + (BUF) * 16384;                                  \
    const __bf16* Bb = Ab + 8192;                                            \
    bf16x8 af[4], bfr[4];                                                    \
    _Pragma("unroll")                                                        \
    for (int fm = 0; fm < 4; ++fm)                                           \
      af[fm] = *(const bf16x8*)(Ab + roA + fm * 512);                        \
    _Pragma("unroll")                                                        \
    for (int fn = 0; fn < 4; ++fn)                                           \
      bfr[fn] = *(const bf16x8*)(Bb + roB + fn * 512);                       \
    if (DOSTAGE) stage((SNEXT) & 3, (SNEXT));                                \
    __builtin_amdgcn_s_barrier();                                            \
    asm volatile("s_waitcnt lgkmcnt(0)" ::: "memory");                       \
    __builtin_amdgcn_s_setprio(1);                                           \
    _Pragma("unroll")                                                        \
    for (int fm = 0; fm < 4; ++fm)                                           \
      _Pragma("unroll")                                                      \
      for (int fn = 0; fn < 4; ++fn)                                         \
        acc[fm][fn] = MF(af[fm], bfr[fn], acc[fm][fn]);                      \
    __builtin_amdgcn_s_setprio(0);                                           \
    __builtin_amdgcn_s_barrier();                                            \
    _Pragma("unroll")                                                        \
    for (int fm = 0; fm < 4; ++fm)                                           \
      af[fm] = *(const bf16x8*)(Ab + roA + (fm + 4) * 512);                  \
    __builtin_amdgcn_s_barrier();                                            \
    asm volatile("s_waitcnt lgkmcnt(0)" ::: "memory");                       \
    __builtin_amdgcn_s_setprio(1);                                           \
    _Pragma("unroll")                                                        \
    for (int fm = 0; fm < 4; ++fm)                                           \
      _Pragma("unroll")                                                      \
      for (int fn = 0; fn < 4; ++fn)                                         \
        acc[fm + 4][fn] = MF(af[fm], bfr[fn], acc[fm + 4][fn]);              \
    __builtin_amdgcn_s_setprio(0);                                           \
    WAITSTMT;                                                                \
    __builtin_amdgcn_s_barrier();                                            \
  }

    // Prologue: fill 3 buffers; wait for buf0 only (vmcnt: 12 -> 8).
    stage(0, 0);
    stage(1, 1);
    stage(2, 2);
    VM8;
    __builtin_amdgcn_s_barrier();

    // Steps 0..123 (buf = s&3, stage s+3, boundary vmcnt(8))
    for (int s = 0; s < 124; s += 4) {
        GSTEP(0, true, s + 3, VM8);
        GSTEP(1, true, s + 4, VM8);
        GSTEP(2, true, s + 5, VM8);
        GSTEP(3, true, s + 6, VM8);
    }
    // Tail: steps 124..127 (stages run out; waits tighten 8 -> 4 -> 0)
    GSTEP(0, true, 127, VM8);    // step 124: last stage (127)
    GSTEP(1, false, 0, VM4);     // step 125: outstanding {126,127} -> need 126
    GSTEP(2, false, 0, VM0);     // step 126: outstanding {127}     -> need 127
    GSTEP(3, false, 0, NOWAIT);  // step 127: nothing outstanding

#undef GSTEP
#undef VM8
#undef VM4
#undef VM0
#undef NOWAIT

    // Epilogue: D layout col = lane&15, row = quad*4 + reg
#pragma unroll
    for (int fm = 0; fm < 8; ++fm) {
        const size_t m0 = mBase + wm * 128 + fm * 16 + quad * 4;
#pragma unroll
        for (int fn = 0; fn < 4; ++fn) {
            const size_t n0 = nBase + wn * 64 + fn * 16 + lb;
            float* p = C + m0 * N + n0;
            p[0 * (size_t)N] = acc[fm][fn][0];
            p[1 * (size_t)N] = acc[fm][fn][1];
            p[2 * (size_t)N] = acc[fm][fn][2];
            p[3 * (size_t)N] = acc[fm][fn][3];
        }
    }
}

// ---------------------------------------------------------------------------
extern "C" void kernel_launch(void* const* d_in, const int* in_sizes, int n_in,
                              void* d_out, int out_size, void* d_ws, size_t ws_size,
                              hipStream_t stream) {
    const float* x      = (const float*)d_in[0];
    const int*   wint   = (const int*)d_in[1];
    const float* wscale = (const float*)d_in[2];
    const float* lA     = (const float*)d_in[3];
    const float* lB     = (const float*)d_in[4];
    float* out = (float*)d_out;

    __bf16* Xb = (__bf16*)d_ws;                                   // M*K*2 = 64 MiB
    __bf16* Wb = (__bf16*)((char*)d_ws + (size_t)M * K * 2);      // N*K*2 = 32 MiB

    qlora_cast_x<<<16384, 256, 0, stream>>>(x, Xb);
    qlora_prep_w<<<256, 256, 0, stream>>>(wint, wscale, lA, lB, Wb);
    qlora_gemm_bt<<<dim3(512), dim3(512), 0, stream>>>(Xb, Wb, out);
}

// Round 3
// 513.546 us; speedup vs baseline: 1.0628x; 1.0628x over previous
//
#include <hip/hip_runtime.h>

// Shapes: B=4, S=2048 -> M=8192; D_IN=K=4096; D_OUT=N=4096; R=16
constexpr int M = 8192;
constexpr int N = 4096;
constexpr int K = 4096;
constexpr float SCALING = 2.0f; // 32/16

typedef __bf16 bf16x8 __attribute__((ext_vector_type(8)));
typedef __bf16 bf16x4 __attribute__((ext_vector_type(4)));
typedef float  f32x4  __attribute__((ext_vector_type(4)));

// ---------------------------------------------------------------------------
// Kernel 1: cast x (fp32) -> bf16 (unchanged)
// ---------------------------------------------------------------------------
__global__ __launch_bounds__(256) void qlora_cast_x(const float* __restrict__ x,
                                                    __bf16* __restrict__ xb) {
    const size_t i = ((size_t)blockIdx.x * 256 + threadIdx.x) * 8;
    const float4 v0 = *(const float4*)(x + i);
    const float4 v1 = *(const float4*)(x + i + 4);
    bf16x8 o;
    o[0] = (__bf16)v0.x; o[1] = (__bf16)v0.y; o[2] = (__bf16)v0.z; o[3] = (__bf16)v0.w;
    o[4] = (__bf16)v1.x; o[5] = (__bf16)v1.y; o[6] = (__bf16)v1.z; o[7] = (__bf16)v1.w;
    *(bf16x8*)(xb + i) = o;
}

// ---------------------------------------------------------------------------
// Kernel 2: W_eff = w_int*scale + 2*loraB@loraA (unchanged from round 1)
// ---------------------------------------------------------------------------
__global__ __launch_bounds__(256) void qlora_prep_w(const int* __restrict__ wi,
                                                    const float* __restrict__ wscale,
                                                    const float* __restrict__ lA,
                                                    const float* __restrict__ lB,
                                                    __bf16* __restrict__ W) {
    __shared__ __align__(16) float As[16][1028];
    const int t  = threadIdx.x;
    const int ol = t >> 4;
    const int kk = t & 15;
    const int o  = blockIdx.x * 16 + ol;
    const float s = wscale[0];
    float b[16];
#pragma unroll
    for (int r = 0; r < 16; ++r) b[r] = lB[o * 16 + r];

    for (int c = 0; c < 4; ++c) {
        const int c0 = c * 1024;
#pragma unroll
        for (int i = 0; i < 16; ++i) {
            const int idx = t + i * 256;
            const int r   = idx >> 8;
            const int c4  = idx & 255;
            const float4 v = *(const float4*)(lA + r * K + c0 + c4 * 4);
            *(float4*)(&As[r][c4 * 4]) = v;
        }
        __syncthreads();
#pragma unroll
        for (int j = 0; j < 16; ++j) {
            const int k4 = kk + j * 16;
            const int kg = c0 + k4 * 4;
            const int4 w4 = *(const int4*)(wi + (size_t)o * K + kg);
            float a0 = 0.f, a1 = 0.f, a2 = 0.f, a3 = 0.f;
#pragma unroll
            for (int r = 0; r < 16; ++r) {
                const float4 a4 = *(const float4*)(&As[r][k4 * 4]);
                a0 += b[r] * a4.x; a1 += b[r] * a4.y;
                a2 += b[r] * a4.z; a3 += b[r] * a4.w;
            }
            bf16x4 v;
            v[0] = (__bf16)((float)w4.x * s + SCALING * a0);
            v[1] = (__bf16)((float)w4.y * s + SCALING * a1);
            v[2] = (__bf16)((float)w4.z * s + SCALING * a2);
            v[3] = (__bf16)((float)w4.w * s + SCALING * a3);
            *(bf16x4*)(W + (size_t)o * K + kg) = v;
        }
        __syncthreads();
    }
}

// ---------------------------------------------------------------------------
// Kernel 3: C[M,N] = Xbf[M,K] @ Wbf[N,K]^T
// 256x256 tile, 8 waves (2Mx4N), BK=32, THREE LDS buffers (96 KiB).
// Software-pipelined register loads: every ds_read has >=1 MFMA cluster
// between issue and consumption (fixes the read/MFMA serialization that
// capped R1/R2 at 46% MfmaUtil).  Per step s (buf = s%3):
//   P1: read afH(s) | stage(s+2) | lgkm(4) [afL/bfr(s) prefetched last step
//       done; afH floats] | cluster1 (afL x bfr, 16 MFMA) | vmcnt(4)
//       [stage(s+1) landed, stage(s+2) in flight] | barrier
//   P2: lgkm(0) [afH done] | cluster2 (afH x bfr, 16 MFMA) with the 8
//       prefetch reads afL/bfr(s+1) from buf(s+1) INTERLEAVED (regs dead at
//       overwrite; zero extra VGPR) | barrier
// Race audit:
//  - stage(s+2) writes buf((s+2)%3)=buf((s-1)%3); all reads of buf(s-1)
//    drained (lgkm) before end-of-(s-1) barrier, stage issued after it.
//  - prefetch reads of buf(s+1) only after mid-step vmcnt(4)+barrier
//    (stage(s+1) landed on all waves, made visible by barrier).
//  - compiler's own waitcnt insertion guarantees ds_read->MFMA deps even if
//    it reorders reads between my asm fences; vmcnt protocol is manual and
//    load-bearing (LDS writes from global_load_lds are not register-tracked).
// LDS swizzle (measured 0 conflicts in R2): chunk c of row r at slot
// c ^ ((r>>1)&3); read slot quad ^ ((lb>>1)&3); staged global chunk
// (l&3)^((l>>3)&3), row l>>2.
// ---------------------------------------------------------------------------
__device__ __forceinline__ void async16(const __bf16* g, __bf16* l) {
    __builtin_amdgcn_global_load_lds(
        (const __attribute__((address_space(1))) unsigned int*)(unsigned long long)g,
        (__attribute__((address_space(3))) unsigned int*)(unsigned int)(unsigned long long)l,
        16, 0, 0);
}

__global__ __launch_bounds__(512, 2) void qlora_gemm_bt(const __bf16* __restrict__ A,
                                                        const __bf16* __restrict__ B,
                                                        float* __restrict__ C) {
    __shared__ __align__(16) __bf16 Lds[49152];   // 3 bufs x [A 8192 | B 8192]

    const int tid  = threadIdx.x;
    const int w    = tid >> 6;
    const int lane = tid & 63;
    const int quad = lane >> 4;
    const int lb   = lane & 15;
    const int wm   = w >> 2;
    const int wn   = w & 3;

    // XCD-aware bijective swizzle (512 blocks = 8 XCDs x 64)
    const int swz = (blockIdx.x & 7) * 64 + (blockIdx.x >> 3);
    const int bx  = swz >> 5;
    const int by  = swz & 31;
    const size_t mBase = (size_t)by * 256;
    const size_t nBase = (size_t)bx * 256;

    // staging: wave w owns rows [w*32, w*32+32) of A and of B
    const int r16 = lane >> 2;
    const int ch  = ((lane & 3) ^ ((lane >> 3) & 3)) * 8;
    const __bf16* gA = A + (mBase + w * 32 + r16) * K + ch;
    const __bf16* gB = B + (nBase + w * 32 + r16) * K + ch;

    // ds_read offsets (elements)
    const int sw  = (quad ^ ((lb >> 1) & 3)) * 8;
    const int roA = (wm * 128 + lb) * 32 + sw;       // + f*512
    const int roB = (wn * 64 + lb) * 32 + sw;        // + f*512

    f32x4 acc[8][4] = {};
    bf16x8 afL[4], afH[4], bfr[4];

    auto stage = [&](int bufe, int s) {
        __bf16* la  = Lds + bufe + w * 1024;
        __bf16* lbp = la + 8192;
        const __bf16* pa = gA + (size_t)s * 32;
        const __bf16* pb = gB + (size_t)s * 32;
        async16(pa, la);
        async16(pa + (size_t)16 * K, la + 512);
        async16(pb, lbp);
        async16(pb + (size_t)16 * K, lbp + 512);
    };

    auto MF = [](bf16x8 a, bf16x8 b, f32x4 c) {
        return __builtin_amdgcn_mfma_f32_16x16x32_bf16(a, b, c, 0, 0, 0);
    };

#define VM4  asm volatile("s_waitcnt vmcnt(4)" ::: "memory")
#define VM0  asm volatile("s_waitcnt vmcnt(0)" ::: "memory")
#define NOVM ((void)0)

    // STEP: BC = buf(s), BN = buf(s+1), B2 = buf(s+2)  (element offsets)
#define STEP(BC, BN, B2, DOSTAGE, MIDWAIT, DOPREF)                           \
  {                                                                          \
    _Pragma("unroll")                                                        \
    for (int f = 0; f < 4; ++f)                                              \
      afH[f] = *(const bf16x8*)(Lds + (BC) + roA + (f + 4) * 512);           \
    if (DOSTAGE) stage((B2), sStage);                                        \
    asm volatile("s_waitcnt lgkmcnt(4)" ::: "memory");                       \
    __builtin_amdgcn_s_setprio(1);                                           \
    _Pragma("unroll")                                                        \
    for (int fm = 0; fm < 4; ++fm)                                           \
      _Pragma("unroll")                                                      \
      for (int fn = 0; fn < 4; ++fn)                                         \
        acc[fm][fn] = MF(afL[fm], bfr[fn], acc[fm][fn]);                     \
    __builtin_amdgcn_s_setprio(0);                                           \
    MIDWAIT;                                                                 \
    __builtin_amdgcn_s_barrier();                                            \
    asm volatile("s_waitcnt lgkmcnt(0)" ::: "memory");                       \
    __builtin_amdgcn_s_setprio(1);                                           \
    _Pragma("unroll")                                                        \
    for (int fn = 0; fn < 4; ++fn) {                                         \
      _Pragma("unroll")                                                      \
      for (int fm = 0; fm < 4; ++fm)                                         \
        acc[fm + 4][fn] = MF(afH[fm], bfr[fn], acc[fm + 4][fn]);             \
      if (DOPREF) {                                                          \
        bfr[fn] = *(const bf16x8*)(Lds + (BN) + 8192 + roB + fn * 512);      \
        afL[fn] = *(const bf16x8*)(Lds + (BN) + roA + fn * 512);             \
      }                                                                      \
    }                                                                        \
    __builtin_amdgcn_s_setprio(0);                                           \
    asm volatile("" ::: "memory");                                           \
    __builtin_amdgcn_s_barrier();                                            \
    ++sStage;                                                                \
  }

    // Prologue: fill bufs 0,1; wait buf0; prefetch step-0 frags.
    int sStage = 2;
    stage(0, 0);
    stage(16384, 1);
    VM4;                                   // 8 outstanding -> 4: stage(0) landed
    __builtin_amdgcn_s_barrier();
#pragma unroll
    for (int f = 0; f < 4; ++f) {
        afL[f] = *(const bf16x8*)(Lds + roA + f * 512);
        bfr[f] = *(const bf16x8*)(Lds + 8192 + roB + f * 512);
    }
    asm volatile("" ::: "memory");

    // Steps 0..125 (42 x 3-step rotation), then 126, 127 with tightening.
    for (int it = 0; it < 42; ++it) {
        STEP(0,     16384, 32768, true, VM4, true);
        STEP(16384, 32768, 0,     true, VM4, true);
        STEP(32768, 0,     16384, true, VM4, true);
    }
    STEP(0,     16384, 32768, false, VM0,  true);   // s=126: stage(127) drained
    STEP(16384, 32768, 0,     false, NOVM, false);  // s=127: nothing outstanding

#undef STEP
#undef VM4
#undef VM0
#undef NOVM

    // Epilogue: D layout col = lane&15, row = quad*4 + reg
#pragma unroll
    for (int fm = 0; fm < 8; ++fm) {
        const size_t m0 = mBase + wm * 128 + fm * 16 + quad * 4;
#pragma unroll
        for (int fn = 0; fn < 4; ++fn) {
            const size_t n0 = nBase + wn * 64 + fn * 16 + lb;
            float* p = C + m0 * N + n0;
            p[0 * (size_t)N] = acc[fm][fn][0];
            p[1 * (size_t)N] = acc[fm][fn][1];
            p[2 * (size_t)N] = acc[fm][fn][2];
            p[3 * (size_t)N] = acc[fm][fn][3];
        }
    }
}

// ---------------------------------------------------------------------------
extern "C" void kernel_launch(void* const* d_in, const int* in_sizes, int n_in,
                              void* d_out, int out_size, void* d_ws, size_t ws_size,
                              hipStream_t stream) {
    const float* x      = (const float*)d_in[0];
    const int*   wint   = (const int*)d_in[1];
    const float* wscale = (const float*)d_in[2];
    const float* lA     = (const float*)d_in[3];
    const float* lB     = (const float*)d_in[4];
    float* out = (float*)d_out;

    __bf16* Xb = (__bf16*)d_ws;                                   // M*K*2 = 64 MiB
    __bf16* Wb = (__bf16*)((char*)d_ws + (size_t)M * K * 2);      // N*K*2 = 32 MiB

    qlora_cast_x<<<16384, 256, 0, stream>>>(x, Xb);
    qlora_prep_w<<<256, 256, 0, stream>>>(wint, wscale, lA, lB, Wb);
    qlora_gemm_bt<<<dim3(512), dim3(512), 0, stream>>>(Xb, Wb, out);
}